// Round 14
// baseline (177.646 us; speedup 1.0000x reference)
//
#include <hip/hip_runtime.h>
#include <cmath>

typedef __bf16 bf16;
typedef bf16 bf16x4 __attribute__((ext_vector_type(4)));
typedef bf16 bf16x8 __attribute__((ext_vector_type(8)));
typedef float f32x4 __attribute__((ext_vector_type(4)));
typedef unsigned int uint;

#define MFMA16(a, b, c) __builtin_amdgcn_mfma_f32_16x16x32_bf16(a, b, c, 0, 0, 0)

// async global->LDS, 16B per lane; LDS dest must be wave-uniform base + lane*16
#define GLOAD16(g, l)                                                   \
  __builtin_amdgcn_global_load_lds(                                     \
      (const __attribute__((address_space(1))) unsigned int*)(g),       \
      (__attribute__((address_space(3))) unsigned int*)(l), 16, 0, 0)

// fp32 -> bf16 bulk convert of x (4Mi), Wqkv (3Mi), Wo (1Mi) in one launch
__global__ __launch_bounds__(256) void cvt_all(
    const float* __restrict__ x, const float* __restrict__ wqkv,
    const float* __restrict__ wo, bf16* __restrict__ xb,
    bf16* __restrict__ wqkvb, bf16* __restrict__ wob) {
  int i = (blockIdx.x * 256 + threadIdx.x) * 4;
  const float* src;
  bf16* dst;
  if (i < (4 << 20)) {
    src = x + i; dst = xb + i;
  } else if (i < (7 << 20)) {
    src = wqkv + (i - (4 << 20)); dst = wqkvb + (i - (4 << 20));
  } else {
    src = wo + (i - (7 << 20)); dst = wob + (i - (7 << 20));
  }
  const f32x4 v = *(const f32x4*)src;
  bf16x4 o = {(bf16)v[0], (bf16)v[1], (bf16)v[2], (bf16)v[3]};
  *(bf16x4*)dst = o;
}

// C[m][n] = sum_k A[m][k] * Bm[n][k]   (NT GEMM, K=1024, 128xBN tile)
// m97 structure: double-buffered LDS, staging via global_load_lds dwordx4,
// one __syncthreads per K-iter.  T1 XCD swizzle [r5/r6: -4us].
// EPI==1 epilogue (n tiles 128-aligned, sec block-uniform):
//   sec<2 : Q/K RoPE, per-element sincos + direct 2B stores (r7: table+repack
//           REGRESSED +10us; stores are already dense 32B sectors).
//   sec==2: V^T via LDS transpose: 16B stores [r2: -15us vs 2B scatter]
// EPI==0: plain fp32 store.
template <int EPI, int BN>
__global__ __launch_bounds__(256) void gemm_nt(
    const bf16* __restrict__ A, const bf16* __restrict__ Bm,
    const int* __restrict__ tokpos,
    bf16* __restrict__ out0, bf16* __restrict__ out1, bf16* __restrict__ out2,
    float* __restrict__ outF, int N) {
  constexpr int NI = BN / 32;  // 16x16 acc frags per wave in N
  constexpr int TSTRIDE = 136; // V-transpose tile row stride (272B = 17*16)
  __shared__ __align__(16) union SMem {
    struct { bf16 A[2][128 * 32]; bf16 B[2][BN * 32]; } st;
    bf16 T[EPI ? 128 * TSTRIDE : 1];
  } sm;
  const int tid = threadIdx.x;
  const int w = tid >> 6, lane = tid & 63, quad = lane >> 4, m16 = lane & 15;
  // XCD-aware block swizzle (bijective: nwg multiple of 8)
  const int nwg = gridDim.x * gridDim.y;
  int bid = blockIdx.y * gridDim.x + blockIdx.x;
  bid = (bid & 7) * (nwg >> 3) + (bid >> 3);
  const int m0 = (bid / gridDim.x) * 128, n0 = (bid % gridDim.x) * BN;
  const int wm = (w >> 1) * 64, wn = (w & 1) * (BN / 2);

  f32x4 acc[4][NI] = {};

  const int row0 = tid >> 2, ch = tid & 3;
  const bf16* Ag0 = A + (size_t)(m0 + row0) * 1024 + ch * 8;
  const bf16* Ag1 = Ag0 + (size_t)64 * 1024;
  const bf16* Bg0 = Bm + (size_t)(n0 + row0) * 1024 + ch * 8;
  const bf16* Bg1 = Bg0 + (size_t)64 * 1024;

  auto STAGE = [&](int p, int k0) {
    GLOAD16(Ag0 + k0, &sm.st.A[p][tid * 8]);
    GLOAD16(Ag1 + k0, &sm.st.A[p][2048 + tid * 8]);
    GLOAD16(Bg0 + k0, &sm.st.B[p][tid * 8]);
    if constexpr (BN == 128) GLOAD16(Bg1 + k0, &sm.st.B[p][2048 + tid * 8]);
  };

  STAGE(0, 0);
  __syncthreads();  // vmcnt(0) drain publishes buffer 0

  int p = 0;
  for (int k0 = 0; k0 < 1024; k0 += 32) {
    const bool more = (k0 + 32) < 1024;
    if (more) STAGE(p ^ 1, k0 + 32);  // async into other buffer
    bf16x8 af[4], bfr[NI];
#pragma unroll
    for (int mi = 0; mi < 4; ++mi)
      af[mi] =
          *(const bf16x8*)(&sm.st.A[p][(wm + mi * 16 + m16) * 32 + quad * 8]);
#pragma unroll
    for (int ni = 0; ni < NI; ++ni)
      bfr[ni] =
          *(const bf16x8*)(&sm.st.B[p][(wn + ni * 16 + m16) * 32 + quad * 8]);
#pragma unroll
    for (int mi = 0; mi < 4; ++mi)
#pragma unroll
      for (int ni = 0; ni < NI; ++ni)
        acc[mi][ni] = MFMA16(af[mi], bfr[ni], acc[mi][ni]);
    if (more) {
      __syncthreads();  // single barrier per iter; drains vmcnt+lgkm
      p ^= 1;
    }
  }

  if constexpr (EPI == 0) {
#pragma unroll
    for (int mi = 0; mi < 4; ++mi) {
      int rowb = m0 + wm + mi * 16 + quad * 4;
#pragma unroll
      for (int r = 0; r < 4; ++r) {
        size_t off = (size_t)(rowb + r) * N + n0 + wn;
#pragma unroll
        for (int ni = 0; ni < NI; ++ni)
          outF[off + ni * 16 + m16] = acc[mi][ni][r];
      }
    }
  } else {
    const int secb = n0 >> 10;  // block-uniform: 0=Q 1=K 2=V
    if (secb == 2) {
      // ---- V: LDS-transpose epilogue ----
      __syncthreads();  // all waves done reading staging bufs
#pragma unroll
      for (int mi = 0; mi < 4; ++mi) {
        int rlb = wm + mi * 16 + quad * 4;  // local row (token) 0..127
#pragma unroll
        for (int ni = 0; ni < 4; ++ni) {
          int c = wn + ni * 16 + m16;  // local col (d-dim) 0..127
          bf16x4 pk = {(bf16)acc[mi][ni][0], (bf16)acc[mi][ni][1],
                       (bf16)acc[mi][ni][2], (bf16)acc[mi][ni][3]};
          *(bf16x4*)(&sm.T[c * TSTRIDE + rlb]) = pk;
        }
      }
      __syncthreads();
      const int bb = m0 >> 11, S0 = m0 & 2047;
      const size_t base = ((size_t)bb * 1024 + (n0 - 2048)) * 2048 + S0;
#pragma unroll
      for (int it = 0; it < 8; ++it) {
        int chunk = it * 256 + tid;
        int c = chunk >> 4, kp = (chunk & 15) * 8;
        bf16x8 v = *(const bf16x8*)(&sm.T[c * TSTRIDE + kp]);
        *(bf16x8*)(out2 + base + (size_t)c * 2048 + kp) = v;
      }
    } else {
      // ---- Q or K with RoPE; partner column is lane^1 in same quad ----
      bf16* dst = secb ? out1 : out0;
      const float sc = secb ? 1.0f : 0.125f;  // fold 1/sqrt(64) into Q
#pragma unroll
      for (int mi = 0; mi < 4; ++mi) {
        int rowb = m0 + wm + mi * 16 + quad * 4;
        int pos4[4];
#pragma unroll
        for (int r = 0; r < 4; ++r) pos4[r] = tokpos[rowb + r];
#pragma unroll
        for (int ni = 0; ni < 4; ++ni) {
          int col = n0 + wn + ni * 16 + m16;
          int f = col & 1023, h = f >> 6, d = f & 63;
          float inv = __expf(-(float)(d & ~1) * (9.2103403719762f / 64.f));
#pragma unroll
          for (int r = 0; r < 4; ++r) {
            float v = acc[mi][ni][r];
            float vp = __shfl_xor(v, 1);
            float ang = (float)pos4[r] * inv;
            float cs, sn;
            __sincosf(ang, &sn, &cs);
            float ov = (d & 1) ? (v * cs + vp * sn) : (v * cs - vp * sn);
            ov *= sc;
            int row = rowb + r;
            int bb = row >> 11, s = row & 2047;
            dst[((size_t)(bb * 16 + h) * 2048 + s) * 64 + d] = (bf16)ov;
          }
        }
      }
    }
  }
}

// Causal flash attention, one 64-row q-tile per block, 1024 blocks,
// j = 31 - blockIdx.y (longest-first; r5/r8/r10/r12: ALL repacking schemes
// regressed -- scheduling is CLOSED). KVBLK=128 (r11), single-buffered K/V,
// 2 barriers/chunk, XOR-granule swizzle via pre-swizzled gload_lds source.
// r13: SWAPPED-OPERAND MFMAs + IN-REGISTER P (no PS LDS strip):
//   QK: sa = mfma(K-frag, Q-frag) -> S^T: thread holds P[key=ni*16+quad*4+r]
//       [q=m16] -- A/B frags have identical lane maps, so ALL LDS reads are
//       unchanged; only the argument order swaps.
//   P->PV-B-frag: fixed 4-quad lane exchange. Target (quad q) needs
//       ap[kk][e] = P[kk*32+q*8+e][m16]; source of key k is quad (k>>2)&3,
//       value W[k>>4] dword (k&3)>>1. Derivation spot-checks:
//       (q=2,m16=7,kk=0,e=5)->srcB quad1,W1,r1 = key 21 OK;
//       (q=0,e=1)->srcA quad0,W0,r1 = key 1 OK;
//       (q=3,kk=1,e=2)->srcA quad2,W3,r2 = key 58 OK.
//       16 __shfl + 8 cndmask replace 16 ds_write_b16 + 2 ds_read_b128 +
//       swizzle addr math + the write->read lgkm stall. PS deleted: 32KB LDS.
//   PV: o = mfma(V^T-frag, ap) -> O^T[d][q]; l-sum is per-thread scalar
//       (q=m16), reduced by 2 shfl_xor; epilogue = 4x 8B vector stores.
// Fixed-shift softmax p=exp(s-8), Q pre-scaled 1/8.
// Q,K: (bh,s,d).  Vt: (bh,d,s).  O: (b,s,h*64+d) bf16.
__global__ __launch_bounds__(256) void attn_kernel(
    const bf16* __restrict__ Q, const bf16* __restrict__ K,
    const bf16* __restrict__ Vt, bf16* __restrict__ O) {
  __shared__ __align__(16) bf16 KP[128 * 64];    // 16KB: 2 key panels
  __shared__ __align__(16) bf16 VP[128 * 64];    // 16KB: 2 key panels
  const int tid = threadIdx.x;
  const int w = tid >> 6, lane = tid & 63, quad = lane >> 4, m16 = lane & 15;
  const int ml = m16 & 7;
  const int bh = blockIdx.x;
  const int j = 31 - blockIdx.y;  // longest q-tiles dispatched first (LPT)
  const bf16* Qb = Q + (size_t)bh * 2048 * 64;
  const bf16* Kb = K + (size_t)bh * 2048 * 64;
  const bf16* Vb = Vt + (size_t)bh * 64 * 2048;

  // staging: thread t covers (row srow=t>>3 within a 32-row group, slot t&7);
  // global source granule is the XOR-swizzled one: c = slot ^ (row&7);
  // +32/64/96-row groups keep row&7 so the same sc applies.
  const int srow = tid >> 3, sc = (tid & 7) ^ (srow & 7);
  const bf16* Kg = Kb + (size_t)srow * 64 + sc * 8;    // + c*8192
  const bf16* Vg = Vb + (size_t)srow * 2048 + sc * 8;  // + c*128
  auto GK = [&](int c) {
    const bf16* kg = Kg + (size_t)c * 8192;
    GLOAD16(kg, &KP[tid * 8]);                      // key rows  0..31
    GLOAD16(kg + 32 * 64, &KP[2048 + tid * 8]);     // key rows 32..63
    GLOAD16(kg + 64 * 64, &KP[4096 + tid * 8]);     // key rows 64..95
    GLOAD16(kg + 96 * 64, &KP[6144 + tid * 8]);     // key rows 96..127
  };
  auto GV = [&](int c) {
    const bf16* vg = Vg + c * 128;
    GLOAD16(vg, &VP[tid * 8]);                          // d 0..31, keys 0..63
    GLOAD16(vg + (size_t)32 * 2048, &VP[2048 + tid * 8]);  // d 32..63
    GLOAD16(vg + 64, &VP[4096 + tid * 8]);              // d 0..31, keys 64..127
    GLOAD16(vg + 64 + (size_t)32 * 2048, &VP[6144 + tid * 8]);
  };

  // Q strip (rows j*64 + w*16 + m16) in A-fragment layout (pre-scaled 1/8);
  // identical bytes serve as the B-operand in the swapped QK.
  const bf16* qrow = Qb + (size_t)(j * 64 + w * 16 + m16) * 64;
  bf16x8 aq[2];
  aq[0] = *(const bf16x8*)(qrow + quad * 8);
  aq[1] = *(const bf16x8*)(qrow + 32 + quad * 8);

  GK(0);
  GV(0);
  __syncthreads();  // vmcnt(0) drain publishes K(0), V(0)

  f32x4 o[4] = {};      // O^T frags: o[ng][r] = O^T[d=ng*16+quad*4+r][q=m16]
  float lsum = 0.f;     // denominator for q = m16 (partial over this quad)
  const int qloc = w * 16 + m16;        // q row within the 64-row tile
  const int srcA = ((lane >> 4) & 1) * 32 + m16;  // quad (2q)&3, same m16
  const int srcB = srcA + 16;                     // quad (2q+1)&3
  const bool hisel = lane >= 32;        // q>>1: selects W[1]/W[3] vs W[0]/W[2]

  // softmax (in-register) + PV against V panel kh; sa = S^T for that panel
  auto SOFTPV = [&](const f32x4* sa, int kh, bool diag) {
    uint W[4][2];  // W[ni] = bf16x4(P[ni*16+quad*4+(0..3)][m16]) as 2 dwords
#pragma unroll
    for (int ni = 0; ni < 4; ++ni) {
      float p4[4];
#pragma unroll
      for (int r = 0; r < 4; ++r) {
        // p = exp(s-8) = exp2(s*log2e - 8*log2e)
        float pp = exp2f(fmaf(sa[ni][r], 1.44269504f, -11.5415603f));
        if (diag && (ni * 16 + quad * 4 + r) > qloc) pp = 0.f;
        lsum += pp;
        p4[r] = pp;
      }
      union { bf16x4 v; uint u[2]; } pk;
      pk.v = (bf16x4){(bf16)p4[0], (bf16)p4[1], (bf16)p4[2], (bf16)p4[3]};
      W[ni][0] = pk.u[0];
      W[ni][1] = pk.u[1];
    }
    // lane exchange: ap[kk][e] = P[kk*32 + quad*8 + e][m16]
    uint a00 = __shfl((int)W[0][0], srcA), a01 = __shfl((int)W[0][1], srcA);
    uint a10 = __shfl((int)W[1][0], srcA), a11 = __shfl((int)W[1][1], srcA);
    uint b00 = __shfl((int)W[0][0], srcB), b01 = __shfl((int)W[0][1], srcB);
    uint b10 = __shfl((int)W[1][0], srcB), b11 = __shfl((int)W[1][1], srcB);
    uint c20 = __shfl((int)W[2][0], srcA), c21 = __shfl((int)W[2][1], srcA);
    uint c30 = __shfl((int)W[3][0], srcA), c31 = __shfl((int)W[3][1], srcA);
    uint d20 = __shfl((int)W[2][0], srcB), d21 = __shfl((int)W[2][1], srcB);
    uint d30 = __shfl((int)W[3][0], srcB), d31 = __shfl((int)W[3][1], srcB);
    union { uint u[4]; bf16x8 v; } ap0, ap1;
    ap0.u[0] = hisel ? a10 : a00;
    ap0.u[1] = hisel ? a11 : a01;
    ap0.u[2] = hisel ? b10 : b00;
    ap0.u[3] = hisel ? b11 : b01;
    ap1.u[0] = hisel ? c30 : c20;
    ap1.u[1] = hisel ? c31 : c21;
    ap1.u[2] = hisel ? d30 : d20;
    ap1.u[3] = hisel ? d31 : d21;
    __builtin_amdgcn_s_setprio(1);
#pragma unroll
    for (int ng = 0; ng < 4; ++ng) {
      bf16x8 bv0 = *(const bf16x8*)(&VP[kh * 4096 + (ng * 16 + m16) * 64 +
                                        ((quad ^ ml) << 3)]);
      o[ng] = MFMA16(bv0, ap0.v, o[ng]);
      bf16x8 bv1 = *(const bf16x8*)(&VP[kh * 4096 + (ng * 16 + m16) * 64 +
                                        (((4 + quad) ^ ml) << 3)]);
      o[ng] = MFMA16(bv1, ap1.v, o[ng]);
    }
    __builtin_amdgcn_s_setprio(0);
  };

  const int NC = (j + 2) >> 1;  // ceil((j+1)/2) 128-key chunks
  for (int c = 0; c < NC; ++c) {
    const bool more = (c + 1) < NC;
    const bool t1 = (2 * c + 1) <= j;  // key tile 2c+1 active?

    // QK^T (swapped: A=K-frag, B=Q-frag -> S^T); reads unchanged
    f32x4 sa0[4] = {}, sa1[4] = {};
    __builtin_amdgcn_s_setprio(1);
#pragma unroll
    for (int kk = 0; kk < 2; ++kk)
#pragma unroll
      for (int ni = 0; ni < 4; ++ni) {
        bf16x8 bk = *(const bf16x8*)(
            &KP[(ni * 16 + m16) * 64 + (((kk * 4 + quad) ^ ml) << 3)]);
        sa0[ni] = MFMA16(bk, aq[kk], sa0[ni]);
      }
    if (t1) {
#pragma unroll
      for (int kk = 0; kk < 2; ++kk)
#pragma unroll
        for (int ni = 0; ni < 4; ++ni) {
          bf16x8 bk = *(const bf16x8*)(
              &KP[4096 + (ni * 16 + m16) * 64 + (((kk * 4 + quad) ^ ml) << 3)]);
          sa1[ni] = MFMA16(bk, aq[kk], sa1[ni]);
        }
    }
    __builtin_amdgcn_s_setprio(0);

    __syncthreads();       // B1: KP free for overwrite; drains V(c) load
    if (more) GK(c + 1);   // async; hides under 2x softmax+PV; drained at B2

    SOFTPV(sa0, 0, 2 * c == j);
    if (t1) SOFTPV(sa1, 1, 2 * c + 1 == j);

    if (more) {
      __syncthreads();  // B2: VP free; K(c+1) drained -> ready for next QK
      GV(c + 1);        // async; hides under next chunk's 32-MFMA QK
    }
  }

  const int b = bh >> 4, hh = bh & 15;
  float l = lsum;
  l += __shfl_xor(l, 16);
  l += __shfl_xor(l, 32);
  float inv_l = 1.f / l;
  const int s = j * 64 + w * 16 + m16;
  const size_t rowoff = (size_t)(b * 2048 + s) * 1024 + hh * 64;
#pragma unroll
  for (int ng = 0; ng < 4; ++ng) {
    bf16x4 pk = {(bf16)(o[ng][0] * inv_l), (bf16)(o[ng][1] * inv_l),
                 (bf16)(o[ng][2] * inv_l), (bf16)(o[ng][3] * inv_l)};
    *(bf16x4*)(O + rowoff + ng * 16 + quad * 4) = pk;
  }
}

extern "C" void kernel_launch(void* const* d_in, const int* in_sizes, int n_in,
                              void* d_out, int out_size, void* d_ws, size_t ws_size,
                              hipStream_t stream) {
  (void)in_sizes; (void)n_in; (void)out_size; (void)ws_size;
  const float* x = (const float*)d_in[0];       // (2,2048,1024) fp32
  const float* Wqkv = (const float*)d_in[1];    // (3072,1024) fp32
  const float* Wo = (const float*)d_in[2];      // (1024,1024) fp32
  const int* tokpos = (const int*)d_in[3];      // (2,2048) int32
  float* out = (float*)d_out;                   // (2,2048,1024) fp32

  const size_t NEL = (size_t)2 * 16 * 2048 * 64;  // 4 Mi elements
  bf16* Qws = (bf16*)d_ws;       // (bh, s, d) RoPE + 1/8 scale   8 MiB
  bf16* Kws = Qws + NEL;         // (bh, s, d) with RoPE          8 MiB
  bf16* Vtw = Kws + NEL;         // (bh, d, s)                    8 MiB
  bf16* Ows = Vtw + NEL;         // (b*s, h*64+d)                 8 MiB
  bf16* xb  = Ows + NEL;         // x in bf16                     8 MiB
  bf16* Wqkvb = xb + NEL;        // W_qkv in bf16                 6 MiB
  bf16* Wob = Wqkvb + (size_t)3072 * 1024;  //                    2 MiB

  // 0) fp32 -> bf16 conversion of all inputs (one launch, 8Mi elements)
  cvt_all<<<8192, 256, 0, stream>>>(x, Wqkv, Wo, xb, Wqkvb, Wob);

  // 1) QKV projection + RoPE + head-layout epilogue: M=4096, N=3072
  gemm_nt<1, 128><<<dim3(24, 32), 256, 0, stream>>>(xb, Wqkvb, tokpos, Qws,
                                                    Kws, Vtw, nullptr, 3072);
  // 2) causal flash attention (1024 blocks, longest-first, KVBLK=128,
  //    in-register P, 32KB LDS)
  attn_kernel<<<dim3(32, 32), 256, 0, stream>>>(Qws, Kws, Vtw, Ows);
  // 3) output projection: M=4096, N=1024, fp32 output, 64-wide N tile
  gemm_nt<0, 64><<<dim3(16, 32), 256, 0, stream>>>(Ows, Wob, nullptr, nullptr,
                                                   nullptr, nullptr, out, 1024);
}

// Round 15
// 176.901 us; speedup vs baseline: 1.0042x; 1.0042x over previous
//
#include <hip/hip_runtime.h>
#include <cmath>

typedef __bf16 bf16;
typedef bf16 bf16x4 __attribute__((ext_vector_type(4)));
typedef bf16 bf16x8 __attribute__((ext_vector_type(8)));
typedef float f32x4 __attribute__((ext_vector_type(4)));

#define MFMA16(a, b, c) __builtin_amdgcn_mfma_f32_16x16x32_bf16(a, b, c, 0, 0, 0)

// async global->LDS, 16B per lane; LDS dest must be wave-uniform base + lane*16
#define GLOAD16(g, l)                                                   \
  __builtin_amdgcn_global_load_lds(                                     \
      (const __attribute__((address_space(1))) unsigned int*)(g),       \
      (__attribute__((address_space(3))) unsigned int*)(l), 16, 0, 0)

// fp32 -> bf16 bulk convert of x (4Mi), Wqkv (3Mi), Wo (1Mi) in one launch
__global__ __launch_bounds__(256) void cvt_all(
    const float* __restrict__ x, const float* __restrict__ wqkv,
    const float* __restrict__ wo, bf16* __restrict__ xb,
    bf16* __restrict__ wqkvb, bf16* __restrict__ wob) {
  int i = (blockIdx.x * 256 + threadIdx.x) * 4;
  const float* src;
  bf16* dst;
  if (i < (4 << 20)) {
    src = x + i; dst = xb + i;
  } else if (i < (7 << 20)) {
    src = wqkv + (i - (4 << 20)); dst = wqkvb + (i - (4 << 20));
  } else {
    src = wo + (i - (7 << 20)); dst = wob + (i - (7 << 20));
  }
  const f32x4 v = *(const f32x4*)src;
  bf16x4 o = {(bf16)v[0], (bf16)v[1], (bf16)v[2], (bf16)v[3]};
  *(bf16x4*)dst = o;
}

// GEMM1: C[m][n] = sum_k A[m][k] * Bm[n][k]  (NT, K=1024, 128x128 tile)
// m97 structure: double-buffered LDS, global_load_lds staging, one barrier
// per K-iter.  T1 XCD swizzle [r5/r6: -4us].
// Epilogue (n tiles 128-aligned, sec block-uniform):
//   sec<2 : Q/K RoPE, per-element sincos + direct 2B stores (r7: table+repack
//           REGRESSED +10us; stores are already dense 32B sectors).
//   sec==2: V^T via LDS transpose: 16B stores [r2: -15us vs 2B scatter]
__global__ __launch_bounds__(256) void gemm_nt(
    const bf16* __restrict__ A, const bf16* __restrict__ Bm,
    const int* __restrict__ tokpos,
    bf16* __restrict__ out0, bf16* __restrict__ out1, bf16* __restrict__ out2) {
  constexpr int TSTRIDE = 136; // V-transpose tile row stride (272B = 17*16)
  __shared__ __align__(16) union SMem {
    struct { bf16 A[2][128 * 32]; bf16 B[2][128 * 32]; } st;
    bf16 T[128 * TSTRIDE];
  } sm;
  const int tid = threadIdx.x;
  const int w = tid >> 6, lane = tid & 63, quad = lane >> 4, m16 = lane & 15;
  // XCD-aware block swizzle (bijective: nwg multiple of 8)
  const int nwg = gridDim.x * gridDim.y;
  int bid = blockIdx.y * gridDim.x + blockIdx.x;
  bid = (bid & 7) * (nwg >> 3) + (bid >> 3);
  const int m0 = (bid / gridDim.x) * 128, n0 = (bid % gridDim.x) * 128;
  const int wm = (w >> 1) * 64, wn = (w & 1) * 64;

  f32x4 acc[4][4] = {};

  const int row0 = tid >> 2, ch = tid & 3;
  const bf16* Ag0 = A + (size_t)(m0 + row0) * 1024 + ch * 8;
  const bf16* Ag1 = Ag0 + (size_t)64 * 1024;
  const bf16* Bg0 = Bm + (size_t)(n0 + row0) * 1024 + ch * 8;
  const bf16* Bg1 = Bg0 + (size_t)64 * 1024;

  auto STAGE = [&](int p, int k0) {
    GLOAD16(Ag0 + k0, &sm.st.A[p][tid * 8]);
    GLOAD16(Ag1 + k0, &sm.st.A[p][2048 + tid * 8]);
    GLOAD16(Bg0 + k0, &sm.st.B[p][tid * 8]);
    GLOAD16(Bg1 + k0, &sm.st.B[p][2048 + tid * 8]);
  };

  STAGE(0, 0);
  __syncthreads();  // vmcnt(0) drain publishes buffer 0

  int p = 0;
  for (int k0 = 0; k0 < 1024; k0 += 32) {
    const bool more = (k0 + 32) < 1024;
    if (more) STAGE(p ^ 1, k0 + 32);  // async into other buffer
    bf16x8 af[4], bfr[4];
#pragma unroll
    for (int mi = 0; mi < 4; ++mi)
      af[mi] =
          *(const bf16x8*)(&sm.st.A[p][(wm + mi * 16 + m16) * 32 + quad * 8]);
#pragma unroll
    for (int ni = 0; ni < 4; ++ni)
      bfr[ni] =
          *(const bf16x8*)(&sm.st.B[p][(wn + ni * 16 + m16) * 32 + quad * 8]);
#pragma unroll
    for (int mi = 0; mi < 4; ++mi)
#pragma unroll
      for (int ni = 0; ni < 4; ++ni)
        acc[mi][ni] = MFMA16(af[mi], bfr[ni], acc[mi][ni]);
    if (more) {
      __syncthreads();  // single barrier per iter; drains vmcnt+lgkm
      p ^= 1;
    }
  }

  const int secb = n0 >> 10;  // block-uniform: 0=Q 1=K 2=V
  if (secb == 2) {
    // ---- V: LDS-transpose epilogue ----
    __syncthreads();  // all waves done reading staging bufs
#pragma unroll
    for (int mi = 0; mi < 4; ++mi) {
      int rlb = wm + mi * 16 + quad * 4;  // local row (token) 0..127
#pragma unroll
      for (int ni = 0; ni < 4; ++ni) {
        int c = wn + ni * 16 + m16;  // local col (d-dim) 0..127
        bf16x4 pk = {(bf16)acc[mi][ni][0], (bf16)acc[mi][ni][1],
                     (bf16)acc[mi][ni][2], (bf16)acc[mi][ni][3]};
        *(bf16x4*)(&sm.T[c * TSTRIDE + rlb]) = pk;
      }
    }
    __syncthreads();
    const int bb = m0 >> 11, S0 = m0 & 2047;
    const size_t base = ((size_t)bb * 1024 + (n0 - 2048)) * 2048 + S0;
#pragma unroll
    for (int it = 0; it < 8; ++it) {
      int chunk = it * 256 + tid;
      int c = chunk >> 4, kp = (chunk & 15) * 8;
      bf16x8 v = *(const bf16x8*)(&sm.T[c * TSTRIDE + kp]);
      *(bf16x8*)(out2 + base + (size_t)c * 2048 + kp) = v;
    }
  } else {
    // ---- Q or K with RoPE; partner column is lane^1 in same quad ----
    bf16* dst = secb ? out1 : out0;
    const float sc = secb ? 1.0f : 0.125f;  // fold 1/sqrt(64) into Q
#pragma unroll
    for (int mi = 0; mi < 4; ++mi) {
      int rowb = m0 + wm + mi * 16 + quad * 4;
      int pos4[4];
#pragma unroll
      for (int r = 0; r < 4; ++r) pos4[r] = tokpos[rowb + r];
#pragma unroll
      for (int ni = 0; ni < 4; ++ni) {
        int col = n0 + wn + ni * 16 + m16;
        int f = col & 1023, h = f >> 6, d = f & 63;
        float inv = __expf(-(float)(d & ~1) * (9.2103403719762f / 64.f));
#pragma unroll
        for (int r = 0; r < 4; ++r) {
          float v = acc[mi][ni][r];
          float vp = __shfl_xor(v, 1);
          float ang = (float)pos4[r] * inv;
          float cs, sn;
          __sincosf(ang, &sn, &cs);
          float ov = (d & 1) ? (v * cs + vp * sn) : (v * cs - vp * sn);
          ov *= sc;
          int row = rowb + r;
          int bb = row >> 11, s = row & 2047;
          dst[((size_t)(bb * 16 + h) * 2048 + s) * 64 + d] = (bf16)ov;
        }
      }
    }
  }
}

// GEMM2 (r15): C[m][n] = sum_k A[m][k]*Wo[n][k], M=4096 N=1024 K=1024,
// fp32 out.  128x64 tile, BK=64: 16 K-iters -> HALF the barriers of the
// old gemm_nt<0,64> (which issued only 8 MFMA/iter/wave against full
// staging+barrier overhead).  Row stride at BK=64 is 128B -> would be a
// 16-way LDS conflict; uses the attn-proven XOR-granule swizzle via
// PRE-SWIZZLED global_load_lds source (byte-identical read pattern to
// attn's KP, measured 0 conflicts r4-r14).  LDS 48KB -> 2 blocks/CU
// (512 blocks).  T1 XCD swizzle (512 % 8 == 0).
__global__ __launch_bounds__(256) void gemm_out(
    const bf16* __restrict__ A, const bf16* __restrict__ Bm,
    float* __restrict__ outF) {
  __shared__ __align__(16) bf16 As[2][128 * 64];  // 32KB
  __shared__ __align__(16) bf16 Bs[2][64 * 64];   // 16KB
  const int tid = threadIdx.x;
  const int w = tid >> 6, lane = tid & 63, quad = lane >> 4, m16 = lane & 15;
  const int ml = m16 & 7;
  const int nwg = gridDim.x * gridDim.y;
  int bid = blockIdx.y * gridDim.x + blockIdx.x;
  bid = (bid & 7) * (nwg >> 3) + (bid >> 3);
  const int m0 = (bid / gridDim.x) * 128, n0 = (bid % gridDim.x) * 64;
  const int wm = (w >> 1) * 64, wn = (w & 1) * 32;

  f32x4 acc[4][2] = {};

  // staging: thread t covers (row srow=t>>3 in a 32-row group, slot t&7);
  // global source granule pre-swizzled: sc = slot ^ (row&7); +32/64/96-row
  // groups keep row&7 -> same sc.
  const int srow = tid >> 3, sc = (tid & 7) ^ (srow & 7);
  const bf16* Ag = A + (size_t)(m0 + srow) * 1024 + sc * 8;
  const bf16* Bg = Bm + (size_t)(n0 + srow) * 1024 + sc * 8;

  auto STAGE = [&](int p, int k0) {
    GLOAD16(Ag + k0, &As[p][tid * 8]);
    GLOAD16(Ag + (size_t)32 * 1024 + k0, &As[p][2048 + tid * 8]);
    GLOAD16(Ag + (size_t)64 * 1024 + k0, &As[p][4096 + tid * 8]);
    GLOAD16(Ag + (size_t)96 * 1024 + k0, &As[p][6144 + tid * 8]);
    GLOAD16(Bg + k0, &Bs[p][tid * 8]);
    GLOAD16(Bg + (size_t)32 * 1024 + k0, &Bs[p][2048 + tid * 8]);
  };

  STAGE(0, 0);
  __syncthreads();  // vmcnt(0) drain publishes buffer 0

  int p = 0;
  for (int k0 = 0; k0 < 1024; k0 += 64) {
    const bool more = (k0 + 64) < 1024;
    if (more) STAGE(p ^ 1, k0 + 64);  // async into other buffer
    bf16x8 af[4][2], bfr[2][2];
#pragma unroll
    for (int mi = 0; mi < 4; ++mi)
#pragma unroll
      for (int kk = 0; kk < 2; ++kk)
        af[mi][kk] = *(const bf16x8*)(
            &As[p][(wm + mi * 16 + m16) * 64 + (((kk * 4 + quad) ^ ml) << 3)]);
#pragma unroll
    for (int ni = 0; ni < 2; ++ni)
#pragma unroll
      for (int kk = 0; kk < 2; ++kk)
        bfr[ni][kk] = *(const bf16x8*)(
            &Bs[p][(wn + ni * 16 + m16) * 64 + (((kk * 4 + quad) ^ ml) << 3)]);
#pragma unroll
    for (int kk = 0; kk < 2; ++kk)
#pragma unroll
      for (int mi = 0; mi < 4; ++mi)
#pragma unroll
        for (int ni = 0; ni < 2; ++ni)
          acc[mi][ni] = MFMA16(af[mi][kk], bfr[ni][kk], acc[mi][ni]);
    if (more) {
      __syncthreads();  // single barrier per iter (16 iters total)
      p ^= 1;
    }
  }

#pragma unroll
  for (int mi = 0; mi < 4; ++mi) {
    int rowb = m0 + wm + mi * 16 + quad * 4;
#pragma unroll
    for (int r = 0; r < 4; ++r) {
      size_t off = (size_t)(rowb + r) * 1024 + n0 + wn;
#pragma unroll
      for (int ni = 0; ni < 2; ++ni)
        outF[off + ni * 16 + m16] = acc[mi][ni][r];
    }
  }
}

// Causal flash attention, one 64-row q-tile per block, 1024 blocks,
// j = 31 - blockIdx.y (longest-first; r5/r8/r10/r12: ALL repacking schemes
// regressed -- scheduling is CLOSED). KVBLK=128 (r11), single-buffered K/V,
// 2 barriers/chunk, XOR-granule swizzle via pre-swizzled gload_lds source.
// r13/r14: in-register P via swapped MFMA + shfl exchange was correct but
// SLOWER (+2.6us: __shfl = ds_bpermute -> 2.2M LDS conflicts + pack VALU).
// The PS-LDS strip below is the measured-best P path. [r11 = 50.2us]
// Fixed-shift softmax p=exp(s-8), Q pre-scaled 1/8.
// Q,K: (bh,s,d).  Vt: (bh,d,s).  O: (b,s,h*64+d) bf16.
__global__ __launch_bounds__(256) void attn_kernel(
    const bf16* __restrict__ Q, const bf16* __restrict__ K,
    const bf16* __restrict__ Vt, bf16* __restrict__ O) {
  __shared__ __align__(16) bf16 KP[128 * 64];    // 16KB: 2 key panels
  __shared__ __align__(16) bf16 VP[128 * 64];    // 16KB: 2 key panels
  __shared__ __align__(16) bf16 PS[4][16 * 64];  // 8KB, per-wave P strip
  const int tid = threadIdx.x;
  const int w = tid >> 6, lane = tid & 63, quad = lane >> 4, m16 = lane & 15;
  const int h8 = m16 >> 3, ml = m16 & 7;
  const int bh = blockIdx.x;
  const int j = 31 - blockIdx.y;  // longest q-tiles dispatched first (LPT)
  const bf16* Qb = Q + (size_t)bh * 2048 * 64;
  const bf16* Kb = K + (size_t)bh * 2048 * 64;
  const bf16* Vb = Vt + (size_t)bh * 64 * 2048;

  // staging: thread t covers (row srow=t>>3 within a 32-row group, slot t&7);
  // global source granule is the XOR-swizzled one: c = slot ^ (row&7);
  // +32/64/96-row groups keep row&7 so the same sc applies.
  const int srow = tid >> 3, sc = (tid & 7) ^ (srow & 7);
  const bf16* Kg = Kb + (size_t)srow * 64 + sc * 8;    // + c*8192
  const bf16* Vg = Vb + (size_t)srow * 2048 + sc * 8;  // + c*128
  auto GK = [&](int c) {
    const bf16* kg = Kg + (size_t)c * 8192;
    GLOAD16(kg, &KP[tid * 8]);                      // key rows  0..31
    GLOAD16(kg + 32 * 64, &KP[2048 + tid * 8]);     // key rows 32..63
    GLOAD16(kg + 64 * 64, &KP[4096 + tid * 8]);     // key rows 64..95
    GLOAD16(kg + 96 * 64, &KP[6144 + tid * 8]);     // key rows 96..127
  };
  auto GV = [&](int c) {
    const bf16* vg = Vg + c * 128;
    GLOAD16(vg, &VP[tid * 8]);                          // d 0..31, keys 0..63
    GLOAD16(vg + (size_t)32 * 2048, &VP[2048 + tid * 8]);  // d 32..63
    GLOAD16(vg + 64, &VP[4096 + tid * 8]);              // d 0..31, keys 64..127
    GLOAD16(vg + 64 + (size_t)32 * 2048, &VP[6144 + tid * 8]);
  };

  // Q strip (rows j*64 + w*16 + m16) in A-fragment layout (pre-scaled 1/8)
  const bf16* qrow = Qb + (size_t)(j * 64 + w * 16 + m16) * 64;
  bf16x8 aq[2];
  aq[0] = *(const bf16x8*)(qrow + quad * 8);
  aq[1] = *(const bf16x8*)(qrow + 32 + quad * 8);

  GK(0);
  GV(0);
  __syncthreads();  // vmcnt(0) drain publishes K(0), V(0)

  f32x4 o[4] = {};
  float l4[4] = {0.f, 0.f, 0.f, 0.f};
  const int qrel = w * 16 + quad * 4;
  bf16* ps = PS[w];

  // softmax + PV against V panel kh; sa = that panel's QK result
  auto SOFTPV = [&](const f32x4* sa, int kh, bool diag) {
#pragma unroll
    for (int r = 0; r < 4; ++r) {
      const int prow = quad * 4 + r;
      const int rb = prow * 64, rx = prow & 7;
#pragma unroll
      for (int ni = 0; ni < 4; ++ni) {
        // p = exp(s-8) = exp2(s*log2e - 8*log2e)
        float pp = exp2f(fmaf(sa[ni][r], 1.44269504f, -11.5415603f));
        if (diag && (ni * 16 + m16) > qrel + r) pp = 0.f;
        l4[r] += pp;
        ps[rb + (((ni * 2 + h8) ^ rx) << 3) + ml] = (bf16)pp;
      }
    }
    // per-wave strip: intra-wave LDS write->read, no barrier needed
    bf16x8 ap[2];
#pragma unroll
    for (int kk = 0; kk < 2; ++kk)
      ap[kk] =
          *(const bf16x8*)(&ps[m16 * 64 + (((kk * 4 + quad) ^ ml) << 3)]);
    __builtin_amdgcn_s_setprio(1);
#pragma unroll
    for (int kk = 0; kk < 2; ++kk)
#pragma unroll
      for (int ng = 0; ng < 4; ++ng) {
        bf16x8 bv = *(const bf16x8*)(&VP[kh * 4096 + (ng * 16 + m16) * 64 +
                                         (((kk * 4 + quad) ^ ml) << 3)]);
        o[ng] = MFMA16(ap[kk], bv, o[ng]);
      }
    __builtin_amdgcn_s_setprio(0);
  };

  const int NC = (j + 2) >> 1;  // ceil((j+1)/2) 128-key chunks
  for (int c = 0; c < NC; ++c) {
    const bool more = (c + 1) < NC;
    const bool t1 = (2 * c + 1) <= j;  // key tile 2c+1 active?

    // QK^T for both panels (swizzled granules: conflict-free ds_read_b128)
    f32x4 sa0[4] = {}, sa1[4] = {};
    __builtin_amdgcn_s_setprio(1);
#pragma unroll
    for (int kk = 0; kk < 2; ++kk)
#pragma unroll
      for (int ni = 0; ni < 4; ++ni) {
        bf16x8 bk = *(const bf16x8*)(
            &KP[(ni * 16 + m16) * 64 + (((kk * 4 + quad) ^ ml) << 3)]);
        sa0[ni] = MFMA16(aq[kk], bk, sa0[ni]);
      }
    if (t1) {
#pragma unroll
      for (int kk = 0; kk < 2; ++kk)
#pragma unroll
        for (int ni = 0; ni < 4; ++ni) {
          bf16x8 bk = *(const bf16x8*)(
              &KP[4096 + (ni * 16 + m16) * 64 + (((kk * 4 + quad) ^ ml) << 3)]);
          sa1[ni] = MFMA16(aq[kk], bk, sa1[ni]);
        }
    }
    __builtin_amdgcn_s_setprio(0);

    __syncthreads();       // B1: KP free for overwrite; drains V(c) load
    if (more) GK(c + 1);   // async; hides under 2x softmax+PV; drained at B2

    SOFTPV(sa0, 0, 2 * c == j);
    if (t1) SOFTPV(sa1, 1, 2 * c + 1 == j);

    if (more) {
      __syncthreads();  // B2: VP free; K(c+1) drained -> ready for next QK
      GV(c + 1);        // async; hides under next chunk's 32-MFMA QK
    }
  }

  const int b = bh >> 4, hh = bh & 15;
#pragma unroll
  for (int r = 0; r < 4; ++r) {
    float l = l4[r];
    l += __shfl_xor(l, 1);
    l += __shfl_xor(l, 2);
    l += __shfl_xor(l, 4);
    l += __shfl_xor(l, 8);
    float inv_l = 1.f / l;
    int s = j * 64 + w * 16 + quad * 4 + r;
    size_t rowoff = (size_t)(b * 2048 + s) * 1024 + hh * 64;
#pragma unroll
    for (int ng = 0; ng < 4; ++ng)
      O[rowoff + ng * 16 + m16] = (bf16)(o[ng][r] * inv_l);
  }
}

extern "C" void kernel_launch(void* const* d_in, const int* in_sizes, int n_in,
                              void* d_out, int out_size, void* d_ws, size_t ws_size,
                              hipStream_t stream) {
  (void)in_sizes; (void)n_in; (void)out_size; (void)ws_size;
  const float* x = (const float*)d_in[0];       // (2,2048,1024) fp32
  const float* Wqkv = (const float*)d_in[1];    // (3072,1024) fp32
  const float* Wo = (const float*)d_in[2];      // (1024,1024) fp32
  const int* tokpos = (const int*)d_in[3];      // (2,2048) int32
  float* out = (float*)d_out;                   // (2,2048,1024) fp32

  const size_t NEL = (size_t)2 * 16 * 2048 * 64;  // 4 Mi elements
  bf16* Qws = (bf16*)d_ws;       // (bh, s, d) RoPE + 1/8 scale   8 MiB
  bf16* Kws = Qws + NEL;         // (bh, s, d) with RoPE          8 MiB
  bf16* Vtw = Kws + NEL;         // (bh, d, s)                    8 MiB
  bf16* Ows = Vtw + NEL;         // (b*s, h*64+d)                 8 MiB
  bf16* xb  = Ows + NEL;         // x in bf16                     8 MiB
  bf16* Wqkvb = xb + NEL;        // W_qkv in bf16                 6 MiB
  bf16* Wob = Wqkvb + (size_t)3072 * 1024;  //                    2 MiB

  // 0) fp32 -> bf16 conversion of all inputs (one launch, 8Mi elements)
  cvt_all<<<8192, 256, 0, stream>>>(x, Wqkv, Wo, xb, Wqkvb, Wob);

  // 1) QKV projection + RoPE + head-layout epilogue: M=4096, N=3072
  gemm_nt<<<dim3(24, 32), 256, 0, stream>>>(xb, Wqkvb, tokpos, Qws, Kws, Vtw);
  // 2) causal flash attention (r11 config: 1024 blocks, longest-first,
  //    KVBLK=128, PS-LDS P strip, 40KB LDS)
  attn_kernel<<<dim3(32, 32), 256, 0, stream>>>(Qws, Kws, Vtw, Ows);
  // 3) output projection: BK=64 + swizzle (half the barriers of the old
  //    BN=64/BK=32 kernel), 512 blocks = 2/CU
  gemm_out<<<dim3(16, 32), 256, 0, stream>>>(Ows, Wob, out);
}

// Round 16
// 173.312 us; speedup vs baseline: 1.0250x; 1.0207x over previous
//
#include <hip/hip_runtime.h>
#include <cmath>

typedef __bf16 bf16;
typedef bf16 bf16x4 __attribute__((ext_vector_type(4)));
typedef bf16 bf16x8 __attribute__((ext_vector_type(8)));
typedef float f32x4 __attribute__((ext_vector_type(4)));

#define MFMA16(a, b, c) __builtin_amdgcn_mfma_f32_16x16x32_bf16(a, b, c, 0, 0, 0)

// async global->LDS, 16B per lane; LDS dest must be wave-uniform base + lane*16
#define GLOAD16(g, l)                                                   \
  __builtin_amdgcn_global_load_lds(                                     \
      (const __attribute__((address_space(1))) unsigned int*)(g),       \
      (__attribute__((address_space(3))) unsigned int*)(l), 16, 0, 0)

// fp32 -> bf16 bulk convert of x (4Mi), Wqkv (3Mi), Wo (1Mi) in one launch
__global__ __launch_bounds__(256) void cvt_all(
    const float* __restrict__ x, const float* __restrict__ wqkv,
    const float* __restrict__ wo, bf16* __restrict__ xb,
    bf16* __restrict__ wqkvb, bf16* __restrict__ wob) {
  int i = (blockIdx.x * 256 + threadIdx.x) * 4;
  const float* src;
  bf16* dst;
  if (i < (4 << 20)) {
    src = x + i; dst = xb + i;
  } else if (i < (7 << 20)) {
    src = wqkv + (i - (4 << 20)); dst = wqkvb + (i - (4 << 20));
  } else {
    src = wo + (i - (7 << 20)); dst = wob + (i - (7 << 20));
  }
  const f32x4 v = *(const f32x4*)src;
  bf16x4 o = {(bf16)v[0], (bf16)v[1], (bf16)v[2], (bf16)v[3]};
  *(bf16x4*)dst = o;
}

// C[m][n] = sum_k A[m][k] * Bm[n][k]   (NT GEMM, K=1024, 128xBN tile)
// m97 structure: double-buffered LDS, staging via global_load_lds dwordx4,
// one __syncthreads per K-iter.
// T1 XCD swizzle [measured r5/r6: non-attn residual -4us].
// r15: BK=64+swizzle GEMM2 variant was NEUTRAL -- the m97 barrier structure
// is the ceiling, not barrier count/conflicts. This template is final.
// EPI==1 epilogue: sec is BLOCK-uniform (n tiles are 128-aligned):
//   sec<2 : Q or K with RoPE, per-element sincos + direct 2B stores.
//           (r7: table+LDS-repack REGRESSED +10us; stores are already
//           dense 32B sectors. Keep as-is.)
//   sec==2: V^T via LDS transpose: 16B stores [r2: -15us vs 2B scatter]
// EPI==0: plain fp32 store.
template <int EPI, int BN>
__global__ __launch_bounds__(256) void gemm_nt(
    const bf16* __restrict__ A, const bf16* __restrict__ Bm,
    const int* __restrict__ tokpos,
    bf16* __restrict__ out0, bf16* __restrict__ out1, bf16* __restrict__ out2,
    float* __restrict__ outF, int N) {
  constexpr int NI = BN / 32;  // 16x16 acc frags per wave in N
  constexpr int TSTRIDE = 136; // V-transpose tile row stride (272B = 17*16)
  __shared__ __align__(16) union SMem {
    struct { bf16 A[2][128 * 32]; bf16 B[2][BN * 32]; } st;
    bf16 T[EPI ? 128 * TSTRIDE : 1];
  } sm;
  const int tid = threadIdx.x;
  const int w = tid >> 6, lane = tid & 63, quad = lane >> 4, m16 = lane & 15;
  // XCD-aware block swizzle (bijective: nwg multiple of 8)
  const int nwg = gridDim.x * gridDim.y;
  int bid = blockIdx.y * gridDim.x + blockIdx.x;
  bid = (bid & 7) * (nwg >> 3) + (bid >> 3);
  const int m0 = (bid / gridDim.x) * 128, n0 = (bid % gridDim.x) * BN;
  const int wm = (w >> 1) * 64, wn = (w & 1) * (BN / 2);

  f32x4 acc[4][NI] = {};

  const int row0 = tid >> 2, ch = tid & 3;
  const bf16* Ag0 = A + (size_t)(m0 + row0) * 1024 + ch * 8;
  const bf16* Ag1 = Ag0 + (size_t)64 * 1024;
  const bf16* Bg0 = Bm + (size_t)(n0 + row0) * 1024 + ch * 8;
  const bf16* Bg1 = Bg0 + (size_t)64 * 1024;

  auto STAGE = [&](int p, int k0) {
    GLOAD16(Ag0 + k0, &sm.st.A[p][tid * 8]);
    GLOAD16(Ag1 + k0, &sm.st.A[p][2048 + tid * 8]);
    GLOAD16(Bg0 + k0, &sm.st.B[p][tid * 8]);
    if constexpr (BN == 128) GLOAD16(Bg1 + k0, &sm.st.B[p][2048 + tid * 8]);
  };

  STAGE(0, 0);
  __syncthreads();  // vmcnt(0) drain publishes buffer 0

  int p = 0;
  for (int k0 = 0; k0 < 1024; k0 += 32) {
    const bool more = (k0 + 32) < 1024;
    if (more) STAGE(p ^ 1, k0 + 32);  // async into other buffer
    bf16x8 af[4], bfr[NI];
#pragma unroll
    for (int mi = 0; mi < 4; ++mi)
      af[mi] =
          *(const bf16x8*)(&sm.st.A[p][(wm + mi * 16 + m16) * 32 + quad * 8]);
#pragma unroll
    for (int ni = 0; ni < NI; ++ni)
      bfr[ni] =
          *(const bf16x8*)(&sm.st.B[p][(wn + ni * 16 + m16) * 32 + quad * 8]);
#pragma unroll
    for (int mi = 0; mi < 4; ++mi)
#pragma unroll
      for (int ni = 0; ni < NI; ++ni)
        acc[mi][ni] = MFMA16(af[mi], bfr[ni], acc[mi][ni]);
    if (more) {
      __syncthreads();  // single barrier per iter; drains vmcnt+lgkm
      p ^= 1;
    }
  }

  if constexpr (EPI == 0) {
#pragma unroll
    for (int mi = 0; mi < 4; ++mi) {
      int rowb = m0 + wm + mi * 16 + quad * 4;
#pragma unroll
      for (int r = 0; r < 4; ++r) {
        size_t off = (size_t)(rowb + r) * N + n0 + wn;
#pragma unroll
        for (int ni = 0; ni < NI; ++ni)
          outF[off + ni * 16 + m16] = acc[mi][ni][r];
      }
    }
  } else {
    const int secb = n0 >> 10;  // block-uniform: 0=Q 1=K 2=V
    if (secb == 2) {
      // ---- V: LDS-transpose epilogue ----
      __syncthreads();  // all waves done reading staging bufs
#pragma unroll
      for (int mi = 0; mi < 4; ++mi) {
        int rlb = wm + mi * 16 + quad * 4;  // local row (token) 0..127
#pragma unroll
        for (int ni = 0; ni < 4; ++ni) {
          int c = wn + ni * 16 + m16;  // local col (d-dim) 0..127
          bf16x4 pk = {(bf16)acc[mi][ni][0], (bf16)acc[mi][ni][1],
                       (bf16)acc[mi][ni][2], (bf16)acc[mi][ni][3]};
          *(bf16x4*)(&sm.T[c * TSTRIDE + rlb]) = pk;
        }
      }
      __syncthreads();
      const int bb = m0 >> 11, S0 = m0 & 2047;
      const size_t base = ((size_t)bb * 1024 + (n0 - 2048)) * 2048 + S0;
#pragma unroll
      for (int it = 0; it < 8; ++it) {
        int chunk = it * 256 + tid;
        int c = chunk >> 4, kp = (chunk & 15) * 8;
        bf16x8 v = *(const bf16x8*)(&sm.T[c * TSTRIDE + kp]);
        *(bf16x8*)(out2 + base + (size_t)c * 2048 + kp) = v;
      }
    } else {
      // ---- Q or K with RoPE; partner column is lane^1 in same quad ----
      bf16* dst = secb ? out1 : out0;
      const float sc = secb ? 1.0f : 0.125f;  // fold 1/sqrt(64) into Q
#pragma unroll
      for (int mi = 0; mi < 4; ++mi) {
        int rowb = m0 + wm + mi * 16 + quad * 4;
        int pos4[4];
#pragma unroll
        for (int r = 0; r < 4; ++r) pos4[r] = tokpos[rowb + r];
#pragma unroll
        for (int ni = 0; ni < 4; ++ni) {
          int col = n0 + wn + ni * 16 + m16;
          int f = col & 1023, h = f >> 6, d = f & 63;
          float inv = __expf(-(float)(d & ~1) * (9.2103403719762f / 64.f));
#pragma unroll
          for (int r = 0; r < 4; ++r) {
            float v = acc[mi][ni][r];
            float vp = __shfl_xor(v, 1);
            float ang = (float)pos4[r] * inv;
            float cs, sn;
            __sincosf(ang, &sn, &cs);
            float ov = (d & 1) ? (v * cs + vp * sn) : (v * cs - vp * sn);
            ov *= sc;
            int row = rowb + r;
            int bb = row >> 11, s = row & 2047;
            dst[((size_t)(bb * 16 + h) * 2048 + s) * 64 + d] = (bf16)ov;
          }
        }
      }
    }
  }
}

// Causal flash attention, one 64-row q-tile per block, 1024 blocks,
// j = 31 - blockIdx.y (longest-first; r5/r8/r10/r12: ALL repacking schemes
// regressed -- scheduling is CLOSED). KVBLK=128 (r11), single-buffered K/V,
// 2 barriers/chunk, XOR-granule swizzle via pre-swizzled gload_lds source.
// r13/r14: in-register P via swapped MFMA + shfl exchange was correct but
// SLOWER (+2.6us: __shfl = ds_bpermute -> 2.2M LDS conflicts + pack VALU).
// The PS-LDS strip below is the measured-best P path. [r11 = 50.2us]
// r16: diag check hoisted to a WAVE-UNIFORM branch -- the old per-element
// `if (diag && ...)` emitted v_cmp+v_cndmask for all 32 elements of EVERY
// chunk, though only each block's final tile is diagonal.
// Fixed-shift softmax p=exp(s-8), Q pre-scaled 1/8.
// Q,K: (bh,s,d).  Vt: (bh,d,s).  O: (b,s,h*64+d) bf16.
__global__ __launch_bounds__(256) void attn_kernel(
    const bf16* __restrict__ Q, const bf16* __restrict__ K,
    const bf16* __restrict__ Vt, bf16* __restrict__ O) {
  __shared__ __align__(16) bf16 KP[128 * 64];    // 16KB: 2 key panels
  __shared__ __align__(16) bf16 VP[128 * 64];    // 16KB: 2 key panels
  __shared__ __align__(16) bf16 PS[4][16 * 64];  // 8KB, per-wave P strip
  const int tid = threadIdx.x;
  const int w = tid >> 6, lane = tid & 63, quad = lane >> 4, m16 = lane & 15;
  const int h8 = m16 >> 3, ml = m16 & 7;
  const int bh = blockIdx.x;
  const int j = 31 - blockIdx.y;  // longest q-tiles dispatched first (LPT)
  const bf16* Qb = Q + (size_t)bh * 2048 * 64;
  const bf16* Kb = K + (size_t)bh * 2048 * 64;
  const bf16* Vb = Vt + (size_t)bh * 64 * 2048;

  // staging: thread t covers (row srow=t>>3 within a 32-row group, slot t&7);
  // global source granule is the XOR-swizzled one: c = slot ^ (row&7);
  // +32/64/96-row groups keep row&7 so the same sc applies.
  const int srow = tid >> 3, sc = (tid & 7) ^ (srow & 7);
  const bf16* Kg = Kb + (size_t)srow * 64 + sc * 8;    // + c*8192
  const bf16* Vg = Vb + (size_t)srow * 2048 + sc * 8;  // + c*128
  auto GK = [&](int c) {
    const bf16* kg = Kg + (size_t)c * 8192;
    GLOAD16(kg, &KP[tid * 8]);                      // key rows  0..31
    GLOAD16(kg + 32 * 64, &KP[2048 + tid * 8]);     // key rows 32..63
    GLOAD16(kg + 64 * 64, &KP[4096 + tid * 8]);     // key rows 64..95
    GLOAD16(kg + 96 * 64, &KP[6144 + tid * 8]);     // key rows 96..127
  };
  auto GV = [&](int c) {
    const bf16* vg = Vg + c * 128;
    GLOAD16(vg, &VP[tid * 8]);                          // d 0..31, keys 0..63
    GLOAD16(vg + (size_t)32 * 2048, &VP[2048 + tid * 8]);  // d 32..63
    GLOAD16(vg + 64, &VP[4096 + tid * 8]);              // d 0..31, keys 64..127
    GLOAD16(vg + 64 + (size_t)32 * 2048, &VP[6144 + tid * 8]);
  };

  // Q strip (rows j*64 + w*16 + m16) in A-fragment layout (pre-scaled 1/8)
  const bf16* qrow = Qb + (size_t)(j * 64 + w * 16 + m16) * 64;
  bf16x8 aq[2];
  aq[0] = *(const bf16x8*)(qrow + quad * 8);
  aq[1] = *(const bf16x8*)(qrow + 32 + quad * 8);

  GK(0);
  GV(0);
  __syncthreads();  // vmcnt(0) drain publishes K(0), V(0)

  f32x4 o[4] = {};
  float l4[4] = {0.f, 0.f, 0.f, 0.f};
  const int qrel = w * 16 + quad * 4;
  bf16* ps = PS[w];

  // softmax + PV against V panel kh; sa = that panel's QK result.
  // diag is a block-uniform branch (j, c uniform): the common (non-diag)
  // path carries no per-element mask compare.
  auto SOFTPV = [&](const f32x4* sa, int kh, bool diag) {
    if (diag) {
#pragma unroll
      for (int r = 0; r < 4; ++r) {
        const int prow = quad * 4 + r;
        const int rb = prow * 64, rx = prow & 7;
#pragma unroll
        for (int ni = 0; ni < 4; ++ni) {
          // p = exp(s-8) = exp2(s*log2e - 8*log2e)
          float pp = exp2f(fmaf(sa[ni][r], 1.44269504f, -11.5415603f));
          if ((ni * 16 + m16) > qrel + r) pp = 0.f;
          l4[r] += pp;
          ps[rb + (((ni * 2 + h8) ^ rx) << 3) + ml] = (bf16)pp;
        }
      }
    } else {
#pragma unroll
      for (int r = 0; r < 4; ++r) {
        const int prow = quad * 4 + r;
        const int rb = prow * 64, rx = prow & 7;
#pragma unroll
        for (int ni = 0; ni < 4; ++ni) {
          float pp = exp2f(fmaf(sa[ni][r], 1.44269504f, -11.5415603f));
          l4[r] += pp;
          ps[rb + (((ni * 2 + h8) ^ rx) << 3) + ml] = (bf16)pp;
        }
      }
    }
    // per-wave strip: intra-wave LDS write->read, no barrier needed
    bf16x8 ap[2];
#pragma unroll
    for (int kk = 0; kk < 2; ++kk)
      ap[kk] =
          *(const bf16x8*)(&ps[m16 * 64 + (((kk * 4 + quad) ^ ml) << 3)]);
    __builtin_amdgcn_s_setprio(1);
#pragma unroll
    for (int kk = 0; kk < 2; ++kk)
#pragma unroll
      for (int ng = 0; ng < 4; ++ng) {
        bf16x8 bv = *(const bf16x8*)(&VP[kh * 4096 + (ng * 16 + m16) * 64 +
                                         (((kk * 4 + quad) ^ ml) << 3)]);
        o[ng] = MFMA16(ap[kk], bv, o[ng]);
      }
    __builtin_amdgcn_s_setprio(0);
  };

  const int NC = (j + 2) >> 1;  // ceil((j+1)/2) 128-key chunks
  for (int c = 0; c < NC; ++c) {
    const bool more = (c + 1) < NC;
    const bool t1 = (2 * c + 1) <= j;  // key tile 2c+1 active?

    // QK^T for both panels (swizzled granules: conflict-free ds_read_b128)
    f32x4 sa0[4] = {}, sa1[4] = {};
    __builtin_amdgcn_s_setprio(1);
#pragma unroll
    for (int kk = 0; kk < 2; ++kk)
#pragma unroll
      for (int ni = 0; ni < 4; ++ni) {
        bf16x8 bk = *(const bf16x8*)(
            &KP[(ni * 16 + m16) * 64 + (((kk * 4 + quad) ^ ml) << 3)]);
        sa0[ni] = MFMA16(aq[kk], bk, sa0[ni]);
      }
    if (t1) {
#pragma unroll
      for (int kk = 0; kk < 2; ++kk)
#pragma unroll
        for (int ni = 0; ni < 4; ++ni) {
          bf16x8 bk = *(const bf16x8*)(
              &KP[4096 + (ni * 16 + m16) * 64 + (((kk * 4 + quad) ^ ml) << 3)]);
          sa1[ni] = MFMA16(aq[kk], bk, sa1[ni]);
        }
    }
    __builtin_amdgcn_s_setprio(0);

    __syncthreads();       // B1: KP free for overwrite; drains V(c) load
    if (more) GK(c + 1);   // async; hides under 2x softmax+PV; drained at B2

    SOFTPV(sa0, 0, 2 * c == j);
    if (t1) SOFTPV(sa1, 1, 2 * c + 1 == j);

    if (more) {
      __syncthreads();  // B2: VP free; K(c+1) drained -> ready for next QK
      GV(c + 1);        // async; hides under next chunk's 32-MFMA QK
    }
  }

  const int b = bh >> 4, hh = bh & 15;
#pragma unroll
  for (int r = 0; r < 4; ++r) {
    float l = l4[r];
    l += __shfl_xor(l, 1);
    l += __shfl_xor(l, 2);
    l += __shfl_xor(l, 4);
    l += __shfl_xor(l, 8);
    float inv_l = 1.f / l;
    int s = j * 64 + w * 16 + quad * 4 + r;
    size_t rowoff = (size_t)(b * 2048 + s) * 1024 + hh * 64;
#pragma unroll
    for (int ng = 0; ng < 4; ++ng)
      O[rowoff + ng * 16 + m16] = (bf16)(o[ng][r] * inv_l);
  }
}

extern "C" void kernel_launch(void* const* d_in, const int* in_sizes, int n_in,
                              void* d_out, int out_size, void* d_ws, size_t ws_size,
                              hipStream_t stream) {
  (void)in_sizes; (void)n_in; (void)out_size; (void)ws_size;
  const float* x = (const float*)d_in[0];       // (2,2048,1024) fp32
  const float* Wqkv = (const float*)d_in[1];    // (3072,1024) fp32
  const float* Wo = (const float*)d_in[2];      // (1024,1024) fp32
  const int* tokpos = (const int*)d_in[3];      // (2,2048) int32
  float* out = (float*)d_out;                   // (2,2048,1024) fp32

  const size_t NEL = (size_t)2 * 16 * 2048 * 64;  // 4 Mi elements
  bf16* Qws = (bf16*)d_ws;       // (bh, s, d) RoPE + 1/8 scale   8 MiB
  bf16* Kws = Qws + NEL;         // (bh, s, d) with RoPE          8 MiB
  bf16* Vtw = Kws + NEL;         // (bh, d, s)                    8 MiB
  bf16* Ows = Vtw + NEL;         // (b*s, h*64+d)                 8 MiB
  bf16* xb  = Ows + NEL;         // x in bf16                     8 MiB
  bf16* Wqkvb = xb + NEL;        // W_qkv in bf16                 6 MiB
  bf16* Wob = Wqkvb + (size_t)3072 * 1024;  //                    2 MiB

  // 0) fp32 -> bf16 conversion of all inputs (one launch, 8Mi elements)
  cvt_all<<<8192, 256, 0, stream>>>(x, Wqkv, Wo, xb, Wqkvb, Wob);

  // 1) QKV projection + RoPE + head-layout epilogue: M=4096, N=3072
  gemm_nt<1, 128><<<dim3(24, 32), 256, 0, stream>>>(xb, Wqkvb, tokpos, Qws,
                                                    Kws, Vtw, nullptr, 3072);
  // 2) causal flash attention (r11 config: 1024 blocks, longest-first,
  //    KVBLK=128, PS-LDS P strip, 40KB LDS) + uniform diag branch
  attn_kernel<<<dim3(32, 32), 256, 0, stream>>>(Qws, Kws, Vtw, Ows);
  // 3) output projection: M=4096, N=1024, fp32 output, 64-wide N tile
  //    (r11's measured-best GEMM2; r15's BK=64 variant was neutral)
  gemm_nt<0, 64><<<dim3(16, 32), 256, 0, stream>>>(Ows, Wob, nullptr, nullptr,
                                                   nullptr, nullptr, out, 1024);
}